// Round 4
// baseline (3004.565 us; speedup 1.0000x reference)
//
#include <hip/hip_runtime.h>
#include <hip/hip_bf16.h>

// Problem constants
#define BB 8
#define TT 2048
#define DD 1024   // d_model (K for QKV gemm)
#define FF 1024   // ff dim

typedef __attribute__((ext_vector_type(8))) short bf16x8;
typedef __attribute__((ext_vector_type(8))) float f32x8;
typedef __attribute__((ext_vector_type(4))) float f32x4;
typedef __attribute__((ext_vector_type(4))) short s16x4;

// softmax scale folded with log2(e) so we can use exp2f
constexpr float kScaleLog2e = 0.03125f * 1.44269504088896340736f;

__device__ __forceinline__ short bf16_bits(float x) {
    __hip_bfloat16 h = __float2bfloat16(x);
    short s;
    __builtin_memcpy(&s, &h, sizeof(short));
    return s;
}

// load 8 consecutive f32 and round to a bf16x8 MFMA fragment
__device__ __forceinline__ bf16x8 cvt8(const float* __restrict__ p) {
    f32x8 f = *(const f32x8*)p;
    bf16x8 r;
#pragma unroll
    for (int i = 0; i < 8; ++i) r[i] = bf16_bits(f[i]);
    return r;
}

// ---------------------------------------------------------------------------
// Kernel 1 (per batch b): q_b/k_b = seq_b @ W^T + bias (f32 in, bf16 out,
// row-major [T, F]);  v_b written TRANSPOSED: vT_b[f][t] (bf16).
// One wave = 16x64 output tile.
// Grid: 3 proj * 128 mtiles * 16 fstripes = 6144 waves = 1536 blocks.
// ---------------------------------------------------------------------------
__global__ __launch_bounds__(256) void qkv_kernel(
    const float* __restrict__ seq_b,
    const float* __restrict__ Wq, const float* __restrict__ bq,
    const float* __restrict__ Wk, const float* __restrict__ bk,
    const float* __restrict__ Wv, const float* __restrict__ bv,
    __hip_bfloat16* __restrict__ q_b, __hip_bfloat16* __restrict__ k_b,
    __hip_bfloat16* __restrict__ vT_b)
{
    const int lane = threadIdx.x & 63;
    const int wid  = blockIdx.x * 4 + (threadIdx.x >> 6);   // [0, 6144)
    const int proj = wid >> 11;          // 0=q 1=k 2=v
    const int rem  = wid & 2047;
    const int m0   = (rem >> 4) * 16;    // t-tile in [0, 2048)
    const int f0   = (rem & 15) * 64;    // 64-wide f stripe

    const float* W    = proj == 0 ? Wq : (proj == 1 ? Wk : Wv);
    const float* bias = proj == 0 ? bq : (proj == 1 ? bk : bv);

    const int mrow = m0 + (lane & 15);
    const int kq   = (lane >> 4) * 8;

    f32x4 z4 = {0.f, 0.f, 0.f, 0.f};
    f32x4 acc[4] = {z4, z4, z4, z4};

    for (int k0 = 0; k0 < DD; k0 += 32) {
        bf16x8 a = cvt8(seq_b + (size_t)mrow * DD + k0 + kq);
#pragma unroll
        for (int j = 0; j < 4; ++j) {
            bf16x8 bfr = cvt8(W + (size_t)(f0 + j * 16 + (lane & 15)) * DD + k0 + kq);
            acc[j] = __builtin_amdgcn_mfma_f32_16x16x32_bf16(a, bfr, acc[j], 0, 0, 0);
        }
    }

    const int quad = lane >> 4;
    if (proj < 2) {
        __hip_bfloat16* out = (proj == 0) ? q_b : k_b;
#pragma unroll
        for (int j = 0; j < 4; ++j) {
            const int col = f0 + j * 16 + (lane & 15);
            const float bv_ = bias[col];
#pragma unroll
            for (int i = 0; i < 4; ++i) {
                const int row = m0 + quad * 4 + i;
                out[(size_t)row * FF + col] = __float2bfloat16(acc[j][i] + bv_);
            }
        }
    } else {
        // transposed store: vT_b[f][t], lane's 4 regs are 4 consecutive t
        const int t_ = m0 + quad * 4;
#pragma unroll
        for (int j = 0; j < 4; ++j) {
            const int col = f0 + j * 16 + (lane & 15);   // f
            const float bv_ = bias[col];
            s16x4 pack;
#pragma unroll
            for (int i = 0; i < 4; ++i) pack[i] = bf16_bits(acc[j][i] + bv_);
            *(s16x4*)(vT_b + (size_t)col * TT + t_) = pack;
        }
    }
}

// ---------------------------------------------------------------------------
// Kernel 2 (per batch b): P[t][s] = exp(scale * q.k) (unnormalized, bf16),
//           Z[t] += row sums of the bf16-ROUNDED P (fp32 atomics) so the
//           normalization in pv matches the numerator exactly.
// One wave: 16 t-rows x 64 s-cols.  Grid: 128 * 32 = 4096 waves = 1024 blocks.
// ---------------------------------------------------------------------------
__global__ __launch_bounds__(256) void score_kernel(
    const __hip_bfloat16* __restrict__ q_b, const __hip_bfloat16* __restrict__ k_b,
    __hip_bfloat16* __restrict__ P, float* __restrict__ Z)
{
    const int lane = threadIdx.x & 63;
    const int wid  = blockIdx.x * 4 + (threadIdx.x >> 6);   // [0, 4096)
    const int t0   = (wid >> 5) * 16;
    const int s0   = (wid & 31) * 64;

    const int mrow = t0 + (lane & 15);
    const int kq   = (lane >> 4) * 8;

    f32x4 z4 = {0.f, 0.f, 0.f, 0.f};
    f32x4 acc[4] = {z4, z4, z4, z4};

    for (int k0 = 0; k0 < FF; k0 += 32) {
        bf16x8 a = *(const bf16x8*)(q_b + (size_t)mrow * FF + k0 + kq);
#pragma unroll
        for (int j = 0; j < 4; ++j) {
            bf16x8 bfr = *(const bf16x8*)(k_b + (size_t)(s0 + j * 16 + (lane & 15)) * FF + k0 + kq);
            acc[j] = __builtin_amdgcn_mfma_f32_16x16x32_bf16(a, bfr, acc[j], 0, 0, 0);
        }
    }

    const int quad = lane >> 4;
    float rsum[4] = {0.f, 0.f, 0.f, 0.f};
#pragma unroll
    for (int j = 0; j < 4; ++j) {
        const int col = s0 + j * 16 + (lane & 15);
#pragma unroll
        for (int i = 0; i < 4; ++i) {
            const float e = exp2f(acc[j][i] * kScaleLog2e);
            const __hip_bfloat16 eb = __float2bfloat16(e);
            rsum[i] += __bfloat162float(eb);   // sum what pv will actually read
            P[(size_t)(t0 + quad * 4 + i) * TT + col] = eb;
        }
    }
    // reduce partial sums across the 16 lanes of this quad-group (bits 0..3)
#pragma unroll
    for (int off = 1; off < 16; off <<= 1) {
#pragma unroll
        for (int i = 0; i < 4; ++i) rsum[i] += __shfl_xor(rsum[i], off, 64);
    }
    if ((lane & 15) == 0) {
#pragma unroll
        for (int i = 0; i < 4; ++i)
            atomicAdd(&Z[t0 + quad * 4 + i], rsum[i]);
    }
}

// ---------------------------------------------------------------------------
// Kernel 3 (per batch b): out_b[t][f] = (P_unnorm @ V) / Z  via vT_b (f32 out)
// One wave: 16 t-rows x 64 f-cols, K=2048.  Grid: 128*16 = 2048 waves = 512 blocks.
// ---------------------------------------------------------------------------
__global__ __launch_bounds__(256) void pv_kernel(
    const __hip_bfloat16* __restrict__ P, const __hip_bfloat16* __restrict__ vT_b,
    const float* __restrict__ Z, float* __restrict__ out_b)
{
    const int lane = threadIdx.x & 63;
    const int wid  = blockIdx.x * 4 + (threadIdx.x >> 6);   // [0, 2048)
    const int t0   = (wid >> 4) * 16;
    const int f0   = (wid & 15) * 64;

    const int mrow = t0 + (lane & 15);
    const int kq   = (lane >> 4) * 8;

    f32x4 z4 = {0.f, 0.f, 0.f, 0.f};
    f32x4 acc[4] = {z4, z4, z4, z4};

    for (int k0 = 0; k0 < TT; k0 += 32) {
        bf16x8 a = *(const bf16x8*)(P + (size_t)mrow * TT + k0 + kq);
#pragma unroll
        for (int j = 0; j < 4; ++j) {
            bf16x8 bfr = *(const bf16x8*)(vT_b + (size_t)(f0 + j * 16 + (lane & 15)) * TT + k0 + kq);
            acc[j] = __builtin_amdgcn_mfma_f32_16x16x32_bf16(a, bfr, acc[j], 0, 0, 0);
        }
    }

    const int quad = lane >> 4;
    float rz[4];
#pragma unroll
    for (int i = 0; i < 4; ++i) rz[i] = 1.0f / Z[t0 + quad * 4 + i];
#pragma unroll
    for (int j = 0; j < 4; ++j) {
        const int col = f0 + j * 16 + (lane & 15);
#pragma unroll
        for (int i = 0; i < 4; ++i) {
            out_b[(size_t)(t0 + quad * 4 + i) * FF + col] = acc[j][i] * rz[i];
        }
    }
}

// ---------------------------------------------------------------------------
extern "C" void kernel_launch(void* const* d_in, const int* in_sizes, int n_in,
                              void* d_out, int out_size, void* d_ws, size_t ws_size,
                              hipStream_t stream) {
    // Reference dtypes are float32 for ALL inputs and the output.
    const float* seq = (const float*)d_in[0];
    const float* Wq  = (const float*)d_in[1];
    const float* bq  = (const float*)d_in[2];
    const float* Wk  = (const float*)d_in[3];
    const float* bk  = (const float*)d_in[4];
    const float* Wv  = (const float*)d_in[5];
    const float* bv  = (const float*)d_in[6];

    // Per-batch workspace layout (total ~20.01 MiB):
    //   Z   :   8 KiB  @ 0
    //   q_b :   4 MiB  @ 8192
    //   k_b :   4 MiB  @ 8192 +  4 MiB
    //   vT_b:   4 MiB  @ 8192 +  8 MiB
    //   P   :   8 MiB  @ 8192 + 12 MiB
    char* ws = (char*)d_ws;
    float*          Z    = (float*)ws;
    __hip_bfloat16* q_b  = (__hip_bfloat16*)(ws + 8192);
    __hip_bfloat16* k_b  = (__hip_bfloat16*)(ws + 8192 + (size_t)4194304);
    __hip_bfloat16* vT_b = (__hip_bfloat16*)(ws + 8192 + (size_t)8388608);
    __hip_bfloat16* P    = (__hip_bfloat16*)(ws + 8192 + (size_t)12582912);
    float* out = (float*)d_out;

    for (int b = 0; b < BB; ++b) {
        const float* seq_b = seq + (size_t)b * TT * DD;
        float*       out_b = out + (size_t)b * TT * FF;

        qkv_kernel<<<1536, 256, 0, stream>>>(seq_b, Wq, bq, Wk, bk, Wv, bv,
                                             q_b, k_b, vT_b);
        hipMemsetAsync(Z, 0, TT * sizeof(float), stream);
        score_kernel<<<1024, 256, 0, stream>>>(q_b, k_b, P, Z);
        pv_kernel<<<512, 256, 0, stream>>>(P, vT_b, Z, out_b);
    }
}

// Round 5
// 537.930 us; speedup vs baseline: 5.5854x; 5.5854x over previous
//
#include <hip/hip_runtime.h>
#include <hip/hip_bf16.h>

// Problem constants
#define BB 8
#define TT 2048
#define DD 1024   // d_model
#define FF 1024   // ff dim

typedef __attribute__((ext_vector_type(8))) short bf16x8;
typedef __attribute__((ext_vector_type(4))) float f32x4;
typedef __attribute__((ext_vector_type(4))) short s16x4;

constexpr float kScaleLog2e = 0.03125f * 1.44269504088896340736f;

__device__ __forceinline__ short bf16_bits(float x) {
    __hip_bfloat16 h = __float2bfloat16(x);
    short s;
    __builtin_memcpy(&s, &h, sizeof(short));
    return s;
}

// ---------------------------------------------------------------------------
// Shared GEMM core: C[128x128] tile = A[128xK] @ B[128xK]^T (both K-major).
// Block = 256 thr = 4 waves in 2x2; wave computes 64x64 via 4x4 MFMA subtiles.
// LDS tiles [128][32] bf16, single-buffered (m93/m97 structure).
// SRC_F32: stage f32 source with on-the-fly bf16 conversion.
// ---------------------------------------------------------------------------
template <bool AF32, bool BF32>
__device__ __forceinline__ void gemm_core(
    const void* __restrict__ Aptr, int lda, int m0,
    const void* __restrict__ Bptr, int ldb, int n0,
    int K, short* As, short* Bs, f32x4 acc[4][4])
{
    const int tid  = threadIdx.x;
    const int lane = tid & 63;
    const int w    = tid >> 6;
    const int wm   = (w & 1) * 64;
    const int wn   = (w >> 1) * 64;
    const int r    = lane & 15;
    const int qd   = lane >> 4;

    for (int k0 = 0; k0 < K; k0 += 32) {
        __syncthreads();
        // ---- cooperative staging: 512 slots of 16B, slot s -> row s/4, col (s%4)*8
#pragma unroll
        for (int it = 0; it < 2; ++it) {
            const int s   = tid + it * 256;
            const int row = s >> 2;
            const int col = (s & 3) << 3;
            // A tile
            if (AF32) {
                const float* p = (const float*)Aptr + (size_t)(m0 + row) * lda + k0 + col;
                f32x4 v0 = *(const f32x4*)p;
                f32x4 v1 = *(const f32x4*)(p + 4);
                bf16x8 o;
#pragma unroll
                for (int i = 0; i < 4; ++i) { o[i] = bf16_bits(v0[i]); o[4 + i] = bf16_bits(v1[i]); }
                *(bf16x8*)(As + row * 32 + col) = o;
            } else {
                *(bf16x8*)(As + row * 32 + col) =
                    *(const bf16x8*)((const short*)Aptr + (size_t)(m0 + row) * lda + k0 + col);
            }
            // B tile
            if (BF32) {
                const float* p = (const float*)Bptr + (size_t)(n0 + row) * ldb + k0 + col;
                f32x4 v0 = *(const f32x4*)p;
                f32x4 v1 = *(const f32x4*)(p + 4);
                bf16x8 o;
#pragma unroll
                for (int i = 0; i < 4; ++i) { o[i] = bf16_bits(v0[i]); o[4 + i] = bf16_bits(v1[i]); }
                *(bf16x8*)(Bs + row * 32 + col) = o;
            } else {
                *(bf16x8*)(Bs + row * 32 + col) =
                    *(const bf16x8*)((const short*)Bptr + (size_t)(n0 + row) * ldb + k0 + col);
            }
        }
        __syncthreads();
        // ---- inner compute: 8 ds_read_b128 + 16 MFMA
        bf16x8 af[4], bf[4];
#pragma unroll
        for (int m = 0; m < 4; ++m)
            af[m] = *(const bf16x8*)(As + (wm + m * 16 + r) * 32 + (qd << 3));
#pragma unroll
        for (int n = 0; n < 4; ++n)
            bf[n] = *(const bf16x8*)(Bs + (wn + n * 16 + r) * 32 + (qd << 3));
#pragma unroll
        for (int m = 0; m < 4; ++m)
#pragma unroll
            for (int n = 0; n < 4; ++n)
                acc[m][n] = __builtin_amdgcn_mfma_f32_16x16x32_bf16(af[m], bf[n], acc[m][n], 0, 0, 0);
    }
}

// ---------------------------------------------------------------------------
// Kernel 1: q/k = seq @ W^T + bias (f32 in, bf16 out); v stored transposed
// vT[b][f][t].  Grid: mtiles * 8 ntiles * 3 proj blocks.
// seq has mtiles*128 rows; q/k row-major [rows][FF]; vT batch via row/2048.
// ---------------------------------------------------------------------------
__global__ __launch_bounds__(256) void qkv_tiled(
    const float* __restrict__ seq,
    const float* __restrict__ Wq, const float* __restrict__ bq,
    const float* __restrict__ Wk, const float* __restrict__ bk,
    const float* __restrict__ Wv, const float* __restrict__ bv,
    __hip_bfloat16* __restrict__ q, __hip_bfloat16* __restrict__ k,
    __hip_bfloat16* __restrict__ vT, int mtiles)
{
    __shared__ short As[128 * 32], Bs[128 * 32];
    const int bid  = blockIdx.x;
    const int mt   = bid % mtiles;
    const int rest = bid / mtiles;
    const int nt   = rest & 7;
    const int proj = rest >> 3;

    const float* W    = proj == 0 ? Wq : (proj == 1 ? Wk : Wv);
    const float* bias = proj == 0 ? bq : (proj == 1 ? bk : bv);

    f32x4 acc[4][4];
#pragma unroll
    for (int m = 0; m < 4; ++m)
#pragma unroll
        for (int n = 0; n < 4; ++n) acc[m][n] = (f32x4){0.f, 0.f, 0.f, 0.f};

    gemm_core<true, true>(seq, DD, mt * 128, W, DD, nt * 128, DD, As, Bs, acc);

    const int lane = threadIdx.x & 63;
    const int w    = threadIdx.x >> 6;
    const int wm   = (w & 1) * 64;
    const int wn   = (w >> 1) * 64;
    const int r    = lane & 15;
    const int qd   = lane >> 4;
    const int row_base = mt * 128 + wm + qd * 4;   // +m*16+i
    const int col_base = nt * 128 + wn + r;        // +n*16

    if (proj < 2) {
        __hip_bfloat16* dst = (proj == 0) ? q : k;
#pragma unroll
        for (int n = 0; n < 4; ++n) {
            const int col = col_base + n * 16;
            const float bv_ = bias[col];
#pragma unroll
            for (int m = 0; m < 4; ++m)
#pragma unroll
                for (int i = 0; i < 4; ++i)
                    dst[(size_t)(row_base + m * 16 + i) * FF + col] =
                        __float2bfloat16(acc[m][n][i] + bv_);
        }
    } else {
        // transposed V store: 4 consecutive t per lane -> 8B packed store
#pragma unroll
        for (int m = 0; m < 4; ++m) {
            const int rowg = row_base + m * 16;
            const int b_   = rowg >> 11;
            const int t_   = rowg & 2047;
            __hip_bfloat16* vb = vT + (size_t)b_ * FF * TT;
#pragma unroll
            for (int n = 0; n < 4; ++n) {
                const int col = col_base + n * 16;
                const float bv_ = bias[col];
                s16x4 pack;
#pragma unroll
                for (int i = 0; i < 4; ++i) pack[i] = bf16_bits(acc[m][n][i] + bv_);
                *(s16x4*)(vb + (size_t)col * TT + t_) = pack;
            }
        }
    }
}

// ---------------------------------------------------------------------------
// Kernel 2: P[b][t][s] = exp(scale*q.k) bf16 (unnormalized), Z[b][t] += rowsum
// of the bf16-rounded values.  Grid: batches*256 blocks (16 tt x 16 st).
// q/k/P/Z are BASE pointers; batch offset from bid>>8.
// ---------------------------------------------------------------------------
__global__ __launch_bounds__(256) void score_tiled(
    const __hip_bfloat16* __restrict__ q, const __hip_bfloat16* __restrict__ k,
    __hip_bfloat16* __restrict__ P, float* __restrict__ Z)
{
    __shared__ short As[128 * 32], Bs[128 * 32];
    const int bid = blockIdx.x;
    const int b   = bid >> 8;
    const int rem = bid & 255;
    const int tt  = rem >> 4;
    const int st  = rem & 15;

    const short* qb = (const short*)q + (size_t)b * TT * FF;
    const short* kb = (const short*)k + (size_t)b * TT * FF;

    f32x4 acc[4][4];
#pragma unroll
    for (int m = 0; m < 4; ++m)
#pragma unroll
        for (int n = 0; n < 4; ++n) acc[m][n] = (f32x4){0.f, 0.f, 0.f, 0.f};

    gemm_core<false, false>(qb, FF, tt * 128, kb, FF, st * 128, FF, As, Bs, acc);

    const int lane = threadIdx.x & 63;
    const int w    = threadIdx.x >> 6;
    const int wm   = (w & 1) * 64;
    const int wn   = (w >> 1) * 64;
    const int r    = lane & 15;
    const int qd   = lane >> 4;
    const int row_base = tt * 128 + wm + qd * 4;
    const int col_base = st * 128 + wn + r;

    __hip_bfloat16* Pb = P + (size_t)b * TT * TT;
    float* Zb = Z + b * TT;

    float rs[4][4];   // [m][i] row partial sums (bf16-rounded, matches pv reads)
#pragma unroll
    for (int m = 0; m < 4; ++m)
#pragma unroll
        for (int i = 0; i < 4; ++i) rs[m][i] = 0.f;

#pragma unroll
    for (int m = 0; m < 4; ++m)
#pragma unroll
        for (int n = 0; n < 4; ++n) {
            const int col = col_base + n * 16;
#pragma unroll
            for (int i = 0; i < 4; ++i) {
                const float e = exp2f(acc[m][n][i] * kScaleLog2e);
                const __hip_bfloat16 eb = __float2bfloat16(e);
                rs[m][i] += __bfloat162float(eb);
                Pb[(size_t)(row_base + m * 16 + i) * TT + col] = eb;
            }
        }
    // reduce across the 16 lanes sharing each row (r = lane&15)
#pragma unroll
    for (int off = 1; off < 16; off <<= 1)
#pragma unroll
        for (int m = 0; m < 4; ++m)
#pragma unroll
            for (int i = 0; i < 4; ++i) rs[m][i] += __shfl_xor(rs[m][i], off, 64);
    if (r == 0) {
#pragma unroll
        for (int m = 0; m < 4; ++m)
#pragma unroll
            for (int i = 0; i < 4; ++i)
                atomicAdd(&Zb[row_base + m * 16 + i], rs[m][i]);
    }
}

// ---------------------------------------------------------------------------
// Kernel 3: out[b][t][f] = (P @ V)/Z via vT.  Grid: batches*128 (16 tt x 8 ft).
// ---------------------------------------------------------------------------
__global__ __launch_bounds__(256) void pv_tiled(
    const __hip_bfloat16* __restrict__ P, const __hip_bfloat16* __restrict__ vT,
    const float* __restrict__ Z, float* __restrict__ out)
{
    __shared__ short As[128 * 32], Bs[128 * 32];
    const int bid = blockIdx.x;
    const int b   = bid >> 7;
    const int rem = bid & 127;
    const int tt  = rem >> 3;
    const int ft  = rem & 7;

    const short* Pb = (const short*)P + (size_t)b * TT * TT;
    const short* vb = (const short*)vT + (size_t)b * FF * TT;

    f32x4 acc[4][4];
#pragma unroll
    for (int m = 0; m < 4; ++m)
#pragma unroll
        for (int n = 0; n < 4; ++n) acc[m][n] = (f32x4){0.f, 0.f, 0.f, 0.f};

    gemm_core<false, false>(Pb, TT, tt * 128, vb, TT, ft * 128, TT, As, Bs, acc);

    const int lane = threadIdx.x & 63;
    const int w    = threadIdx.x >> 6;
    const int wm   = (w & 1) * 64;
    const int wn   = (w >> 1) * 64;
    const int r    = lane & 15;
    const int qd   = lane >> 4;
    const int row_base = tt * 128 + wm + qd * 4;
    const int col_base = ft * 128 + wn + r;

    const float* Zb = Z + b * TT;
    float* ob = out + (size_t)b * TT * FF;

#pragma unroll
    for (int m = 0; m < 4; ++m) {
        float rz[4];
#pragma unroll
        for (int i = 0; i < 4; ++i) rz[i] = 1.0f / Zb[row_base + m * 16 + i];
#pragma unroll
        for (int n = 0; n < 4; ++n) {
            const int col = col_base + n * 16;
#pragma unroll
            for (int i = 0; i < 4; ++i)
                ob[(size_t)(row_base + m * 16 + i) * FF + col] = acc[m][n][i] * rz[i];
        }
    }
}

// ---------------------------------------------------------------------------
extern "C" void kernel_launch(void* const* d_in, const int* in_sizes, int n_in,
                              void* d_out, int out_size, void* d_ws, size_t ws_size,
                              hipStream_t stream) {
    const float* seq = (const float*)d_in[0];
    const float* Wq  = (const float*)d_in[1];
    const float* bq  = (const float*)d_in[2];
    const float* Wk  = (const float*)d_in[3];
    const float* bk  = (const float*)d_in[4];
    const float* Wv  = (const float*)d_in[5];
    const float* bv  = (const float*)d_in[6];
    float* out = (float*)d_out;
    char* ws = (char*)d_ws;

    const size_t MB32 = 33554432;       // q/k/vT each (bf16 [16384][1024] / [8][1024][2048])
    const size_t PFULL = 67108864;      // P bf16 [8][2048][2048]
    const size_t TIER1 = 3 * MB32 + PFULL + 65536;   // 167,837,696
    const size_t TIER2 = 3 * MB32 + 8388608 + 65536; // 109,117,440

    if (ws_size >= TIER1) {
        // ---- Tier 1: everything resident, 4 dispatches
        __hip_bfloat16* q  = (__hip_bfloat16*)(ws);
        __hip_bfloat16* k  = (__hip_bfloat16*)(ws + MB32);
        __hip_bfloat16* vT = (__hip_bfloat16*)(ws + 2 * MB32);
        __hip_bfloat16* P  = (__hip_bfloat16*)(ws + 3 * MB32);
        float*          Z  = (float*)(ws + 3 * MB32 + PFULL);

        hipMemsetAsync(Z, 0, (size_t)BB * TT * sizeof(float), stream);
        qkv_tiled<<<128 * 8 * 3, 256, 0, stream>>>(seq, Wq, bq, Wk, bk, Wv, bv,
                                                   q, k, vT, 128);
        score_tiled<<<BB * 256, 256, 0, stream>>>(q, k, P, Z);
        pv_tiled<<<BB * 128, 256, 0, stream>>>(P, vT, Z, out);
    } else if (ws_size >= TIER2) {
        // ---- Tier 2: batched qkv, per-batch score/pv with shared 8MB P
        __hip_bfloat16* q  = (__hip_bfloat16*)(ws);
        __hip_bfloat16* k  = (__hip_bfloat16*)(ws + MB32);
        __hip_bfloat16* vT = (__hip_bfloat16*)(ws + 2 * MB32);
        __hip_bfloat16* P  = (__hip_bfloat16*)(ws + 3 * MB32);
        float*          Z  = (float*)(ws + 3 * MB32 + 8388608);

        hipMemsetAsync(Z, 0, (size_t)BB * TT * sizeof(float), stream);
        qkv_tiled<<<128 * 8 * 3, 256, 0, stream>>>(seq, Wq, bq, Wk, bk, Wv, bv,
                                                   q, k, vT, 128);
        for (int b = 0; b < BB; ++b) {
            score_tiled<<<256, 256, 0, stream>>>(q + (size_t)b * TT * FF,
                                                 k + (size_t)b * TT * FF, P, Z + b * TT);
            pv_tiled<<<128, 256, 0, stream>>>(P, vT + (size_t)b * FF * TT,
                                              Z + b * TT, out + (size_t)b * TT * FF);
        }
    } else {
        // ---- Tier 3: proven 20MB per-batch pipeline
        float*          Z    = (float*)ws;
        __hip_bfloat16* q_b  = (__hip_bfloat16*)(ws + 8192);
        __hip_bfloat16* k_b  = (__hip_bfloat16*)(ws + 8192 + (size_t)4194304);
        __hip_bfloat16* vT_b = (__hip_bfloat16*)(ws + 8192 + (size_t)8388608);
        __hip_bfloat16* P    = (__hip_bfloat16*)(ws + 8192 + (size_t)12582912);

        for (int b = 0; b < BB; ++b) {
            const float* seq_b = seq + (size_t)b * TT * DD;
            qkv_tiled<<<16 * 8 * 3, 256, 0, stream>>>(seq_b, Wq, bq, Wk, bk, Wv, bv,
                                                      q_b, k_b, vT_b, 16);
            hipMemsetAsync(Z, 0, TT * sizeof(float), stream);
            score_tiled<<<256, 256, 0, stream>>>(q_b, k_b, P, Z);
            pv_tiled<<<128, 256, 0, stream>>>(P, vT_b, Z, out + (size_t)b * TT * FF);
        }
    }
}

// Round 6
// 469.152 us; speedup vs baseline: 6.4042x; 1.1466x over previous
//
#include <hip/hip_runtime.h>
#include <hip/hip_bf16.h>

// Problem constants
#define BB 8
#define TT 2048
#define DD 1024   // d_model
#define FF 1024   // ff dim

typedef __attribute__((ext_vector_type(8))) short bf16x8;
typedef __attribute__((ext_vector_type(4))) float f32x4;
typedef __attribute__((ext_vector_type(4))) short s16x4;

constexpr float kScaleLog2e = 0.03125f * 1.44269504088896340736f;

__device__ __forceinline__ short bf16_bits(float x) {
    __hip_bfloat16 h = __float2bfloat16(x);
    short s;
    __builtin_memcpy(&s, &h, sizeof(short));
    return s;
}

// ---------------------------------------------------------------------------
// f32 -> bf16 convert (8 elems/thread, 32B in / 16B out per lane)
// ---------------------------------------------------------------------------
__global__ __launch_bounds__(256) void cvt_kernel(
    const float* __restrict__ src, short* __restrict__ dst, int n8)
{
    const int i = blockIdx.x * 256 + threadIdx.x;
    if (i < n8) {
        f32x4 a = ((const f32x4*)src)[2 * i];
        f32x4 b = ((const f32x4*)src)[2 * i + 1];
        bf16x8 o;
#pragma unroll
        for (int j = 0; j < 4; ++j) { o[j] = bf16_bits(a[j]); o[4 + j] = bf16_bits(b[j]); }
        ((bf16x8*)dst)[i] = o;
    }
}

// ---------------------------------------------------------------------------
// Shared bf16 GEMM core: C[128x128] = A[128xK] @ B[128xK]^T (both K-major).
// 256 thr = 4 waves (2x2); wave = 64x64 via 4x4 MFMA subtiles.
// LDS [128][32] bf16 per operand; staging via global_load_lds width=16:
// slot s = tid + it*256 -> LDS byte s*16 (lane-contiguous per wave, m104-safe),
// global row s/4, col (s%4)*8.
// ---------------------------------------------------------------------------
__device__ __forceinline__ void gemm_core(
    const short* __restrict__ A, int lda, int m0,
    const short* __restrict__ B, int ldb, int n0,
    int K, short* As, short* Bs, f32x4 acc[4][4])
{
    const int tid  = threadIdx.x;
    const int lane = tid & 63;
    const int w    = tid >> 6;
    const int wm   = (w & 1) * 64;
    const int wn   = (w >> 1) * 64;
    const int r    = lane & 15;
    const int qd   = lane >> 4;

    for (int k0 = 0; k0 < K; k0 += 32) {
        __syncthreads();
#pragma unroll
        for (int it = 0; it < 2; ++it) {
            const int s   = tid + it * 256;
            const int row = s >> 2;
            const int col = (s & 3) << 3;
            __builtin_amdgcn_global_load_lds(
                (const __attribute__((address_space(1))) unsigned int*)
                    (A + (size_t)(m0 + row) * lda + k0 + col),
                (__attribute__((address_space(3))) unsigned int*)(As + s * 8),
                16, 0, 0);
            __builtin_amdgcn_global_load_lds(
                (const __attribute__((address_space(1))) unsigned int*)
                    (B + (size_t)(n0 + row) * ldb + k0 + col),
                (__attribute__((address_space(3))) unsigned int*)(Bs + s * 8),
                16, 0, 0);
        }
        __syncthreads();
        bf16x8 af[4], bf[4];
#pragma unroll
        for (int m = 0; m < 4; ++m)
            af[m] = *(const bf16x8*)(As + (wm + m * 16 + r) * 32 + (qd << 3));
#pragma unroll
        for (int n = 0; n < 4; ++n)
            bf[n] = *(const bf16x8*)(Bs + (wn + n * 16 + r) * 32 + (qd << 3));
#pragma unroll
        for (int m = 0; m < 4; ++m)
#pragma unroll
            for (int n = 0; n < 4; ++n)
                acc[m][n] = __builtin_amdgcn_mfma_f32_16x16x32_bf16(af[m], bf[n], acc[m][n], 0, 0, 0);
    }
}

// ---------------------------------------------------------------------------
// Kernel 1: q/k = seqb @ Wb^T + bias (bf16 in, bf16 out); v transposed
// vT[b][f][t].  Grid 3072: nt/proj fastest so 24 consecutive blocks share
// the same A row-stripe (L2/L3 locality).
// ---------------------------------------------------------------------------
__global__ __launch_bounds__(256) void qkv_tiled(
    const short* __restrict__ seqb, const short* __restrict__ Wb,
    const float* __restrict__ bq, const float* __restrict__ bk,
    const float* __restrict__ bv,
    __hip_bfloat16* __restrict__ q, __hip_bfloat16* __restrict__ k,
    __hip_bfloat16* __restrict__ vT)
{
    __shared__ short As[128 * 32], Bs[128 * 32];
    const int bid  = blockIdx.x;
    const int mt   = bid / 24;
    const int rest = bid % 24;
    const int nt   = rest & 7;
    const int proj = rest >> 3;

    const short* W    = Wb + (size_t)proj * FF * DD;
    const float* bias = proj == 0 ? bq : (proj == 1 ? bk : bv);

    f32x4 acc[4][4];
#pragma unroll
    for (int m = 0; m < 4; ++m)
#pragma unroll
        for (int n = 0; n < 4; ++n) acc[m][n] = (f32x4){0.f, 0.f, 0.f, 0.f};

    gemm_core(seqb, DD, mt * 128, W, DD, nt * 128, DD, As, Bs, acc);

    const int lane = threadIdx.x & 63;
    const int w    = threadIdx.x >> 6;
    const int wm   = (w & 1) * 64;
    const int wn   = (w >> 1) * 64;
    const int r    = lane & 15;
    const int qd   = lane >> 4;
    const int row_base = mt * 128 + wm + qd * 4;   // +m*16+i
    const int col_base = nt * 128 + wn + r;        // +n*16

    if (proj < 2) {
        __hip_bfloat16* dst = (proj == 0) ? q : k;
#pragma unroll
        for (int n = 0; n < 4; ++n) {
            const int col = col_base + n * 16;
            const float bv_ = bias[col];
#pragma unroll
            for (int m = 0; m < 4; ++m)
#pragma unroll
                for (int i = 0; i < 4; ++i)
                    dst[(size_t)(row_base + m * 16 + i) * FF + col] =
                        __float2bfloat16(acc[m][n][i] + bv_);
        }
    } else {
        // transposed V: lane's 4 regs = 4 consecutive t -> 8B packed store
#pragma unroll
        for (int m = 0; m < 4; ++m) {
            const int rowg = row_base + m * 16;
            const int b_   = rowg >> 11;
            const int t_   = rowg & 2047;
            __hip_bfloat16* vb = vT + (size_t)b_ * FF * TT;
#pragma unroll
            for (int n = 0; n < 4; ++n) {
                const int col = col_base + n * 16;
                const float bv_ = bias[col];
                s16x4 pack;
#pragma unroll
                for (int i = 0; i < 4; ++i) pack[i] = bf16_bits(acc[m][n][i] + bv_);
                *(s16x4*)(vb + (size_t)col * TT + t_) = pack;
            }
        }
    }
}

// ---------------------------------------------------------------------------
// Kernel 2: P[b][t][s] = exp(scale*q.k) bf16 (unnormalized), Z[b][t] += rowsum
// of bf16-rounded values.  Grid: 8 * 256 (st fastest -> q-tile reuse).
// ---------------------------------------------------------------------------
__global__ __launch_bounds__(256) void score_tiled(
    const __hip_bfloat16* __restrict__ q, const __hip_bfloat16* __restrict__ k,
    __hip_bfloat16* __restrict__ P, float* __restrict__ Z)
{
    __shared__ short As[128 * 32], Bs[128 * 32];
    const int bid = blockIdx.x;
    const int b   = bid >> 8;
    const int rem = bid & 255;
    const int tt  = rem >> 4;
    const int st  = rem & 15;

    const short* qb = (const short*)q + (size_t)b * TT * FF;
    const short* kb = (const short*)k + (size_t)b * TT * FF;

    f32x4 acc[4][4];
#pragma unroll
    for (int m = 0; m < 4; ++m)
#pragma unroll
        for (int n = 0; n < 4; ++n) acc[m][n] = (f32x4){0.f, 0.f, 0.f, 0.f};

    gemm_core(qb, FF, tt * 128, kb, FF, st * 128, FF, As, Bs, acc);

    const int lane = threadIdx.x & 63;
    const int w    = threadIdx.x >> 6;
    const int wm   = (w & 1) * 64;
    const int wn   = (w >> 1) * 64;
    const int r    = lane & 15;
    const int qd   = lane >> 4;
    const int row_base = tt * 128 + wm + qd * 4;
    const int col_base = st * 128 + wn + r;

    __hip_bfloat16* Pb = P + (size_t)b * TT * TT;
    float* Zb = Z + b * TT;

    float rs[4][4];
#pragma unroll
    for (int m = 0; m < 4; ++m)
#pragma unroll
        for (int i = 0; i < 4; ++i) rs[m][i] = 0.f;

#pragma unroll
    for (int m = 0; m < 4; ++m)
#pragma unroll
        for (int n = 0; n < 4; ++n) {
            const int col = col_base + n * 16;
#pragma unroll
            for (int i = 0; i < 4; ++i) {
                const float e = exp2f(acc[m][n][i] * kScaleLog2e);
                const __hip_bfloat16 eb = __float2bfloat16(e);
                rs[m][i] += __bfloat162float(eb);
                Pb[(size_t)(row_base + m * 16 + i) * TT + col] = eb;
            }
        }
#pragma unroll
    for (int off = 1; off < 16; off <<= 1)
#pragma unroll
        for (int m = 0; m < 4; ++m)
#pragma unroll
            for (int i = 0; i < 4; ++i) rs[m][i] += __shfl_xor(rs[m][i], off, 64);
    if (r == 0) {
#pragma unroll
        for (int m = 0; m < 4; ++m)
#pragma unroll
            for (int i = 0; i < 4; ++i)
                atomicAdd(&Zb[row_base + m * 16 + i], rs[m][i]);
    }
}

// ---------------------------------------------------------------------------
// Kernel 3: out[b][t][f] = (P @ V)/Z via vT.  Grid: 8 * 128 (ft fastest).
// ---------------------------------------------------------------------------
__global__ __launch_bounds__(256) void pv_tiled(
    const __hip_bfloat16* __restrict__ P, const __hip_bfloat16* __restrict__ vT,
    const float* __restrict__ Z, float* __restrict__ out)
{
    __shared__ short As[128 * 32], Bs[128 * 32];
    const int bid = blockIdx.x;
    const int b   = bid >> 7;
    const int rem = bid & 127;
    const int tt  = rem >> 3;
    const int ft  = rem & 7;

    const short* Pb = (const short*)P + (size_t)b * TT * TT;
    const short* vb = (const short*)vT + (size_t)b * FF * TT;

    f32x4 acc[4][4];
#pragma unroll
    for (int m = 0; m < 4; ++m)
#pragma unroll
        for (int n = 0; n < 4; ++n) acc[m][n] = (f32x4){0.f, 0.f, 0.f, 0.f};

    gemm_core(Pb, TT, tt * 128, vb, TT, ft * 128, TT, As, Bs, acc);

    const int lane = threadIdx.x & 63;
    const int w    = threadIdx.x >> 6;
    const int wm   = (w & 1) * 64;
    const int wn   = (w >> 1) * 64;
    const int r    = lane & 15;
    const int qd   = lane >> 4;
    const int row_base = tt * 128 + wm + qd * 4;
    const int col_base = ft * 128 + wn + r;

    const float* Zb = Z + b * TT;
    float* ob = out + (size_t)b * TT * FF;

#pragma unroll
    for (int m = 0; m < 4; ++m) {
        float rz[4];
#pragma unroll
        for (int i = 0; i < 4; ++i) rz[i] = 1.0f / Zb[row_base + m * 16 + i];
#pragma unroll
        for (int n = 0; n < 4; ++n) {
            const int col = col_base + n * 16;
#pragma unroll
            for (int i = 0; i < 4; ++i)
                ob[(size_t)(row_base + m * 16 + i) * FF + col] = acc[m][n][i] * rz[i];
        }
    }
}

// ---------------------------------------------------------------------------
extern "C" void kernel_launch(void* const* d_in, const int* in_sizes, int n_in,
                              void* d_out, int out_size, void* d_ws, size_t ws_size,
                              hipStream_t stream) {
    const float* seq = (const float*)d_in[0];
    const float* Wq  = (const float*)d_in[1];
    const float* bq  = (const float*)d_in[2];
    const float* Wk  = (const float*)d_in[3];
    const float* bk  = (const float*)d_in[4];
    const float* Wv  = (const float*)d_in[5];
    const float* bv  = (const float*)d_in[6];
    float* out = (float*)d_out;
    char* ws = (char*)d_ws;

    // Workspace (exactly 167,837,696 B — the bound proven by round 5's tier-1):
    //   q   : 32 MiB @ 0
    //   k   : 32 MiB @ 33554432
    //   vT  : 32 MiB @ 67108864
    //   P   : 64 MiB @ 100663296   (seqb [32 MiB] and Wb [6 MiB] alias P's
    //                               region; both dead before score writes P)
    //   Z   : 64 KiB @ 167772160
    const size_t MB32 = 33554432;
    __hip_bfloat16* q   = (__hip_bfloat16*)(ws);
    __hip_bfloat16* k   = (__hip_bfloat16*)(ws + MB32);
    __hip_bfloat16* vT  = (__hip_bfloat16*)(ws + 2 * MB32);
    __hip_bfloat16* P   = (__hip_bfloat16*)(ws + 3 * MB32);
    float*          Z   = (float*)(ws + 3 * MB32 + (size_t)67108864);
    short*          seqb = (short*)P;                              // 32 MiB
    short*          Wb   = (short*)((char*)P + MB32);              //  6 MiB (3 x 2 MiB)

    hipMemsetAsync(Z, 0, (size_t)BB * TT * sizeof(float), stream);

    // f32 -> bf16 converts: seq (16.8M elems) and Wq/Wk/Wv (1M each)
    cvt_kernel<<<8192, 256, 0, stream>>>(seq, seqb, (BB * TT * DD) / 8);
    cvt_kernel<<<512, 256, 0, stream>>>(Wq, Wb,                         (FF * DD) / 8);
    cvt_kernel<<<512, 256, 0, stream>>>(Wk, Wb + (size_t)FF * DD,       (FF * DD) / 8);
    cvt_kernel<<<512, 256, 0, stream>>>(Wv, Wb + (size_t)2 * FF * DD,   (FF * DD) / 8);

    qkv_tiled<<<128 * 24, 256, 0, stream>>>(seqb, Wb, bq, bk, bv, q, k, vT);
    score_tiled<<<BB * 256, 256, 0, stream>>>(q, k, P, Z);
    pv_tiled<<<BB * 128, 256, 0, stream>>>(P, vT, Z, out);
}

// Round 7
// 451.100 us; speedup vs baseline: 6.6605x; 1.0400x over previous
//
#include <hip/hip_runtime.h>
#include <hip/hip_bf16.h>

// Problem constants
#define BB 8
#define TT 2048
#define DD 1024   // d_model
#define FF 1024   // ff dim

typedef __attribute__((ext_vector_type(8))) short bf16x8;
typedef __attribute__((ext_vector_type(4))) float f32x4;
typedef __attribute__((ext_vector_type(4))) short s16x4;

constexpr float kScaleLog2e = 0.03125f * 1.44269504088896340736f;

__device__ __forceinline__ short bf16_bits(float x) {
    __hip_bfloat16 h = __float2bfloat16(x);
    short s;
    __builtin_memcpy(&s, &h, sizeof(short));
    return s;
}

// ---------------------------------------------------------------------------
// Merged f32 -> bf16 convert: seq (8192 blocks) + Wq/Wk/Wv (512 each).
// 8 elems/thread.
// ---------------------------------------------------------------------------
__global__ __launch_bounds__(256) void cvt_all(
    const float* __restrict__ seq, const float* __restrict__ Wq,
    const float* __restrict__ Wk, const float* __restrict__ Wv,
    short* __restrict__ seqb, short* __restrict__ Wb)
{
    const int bid = blockIdx.x;
    const float* src;
    short* dst;
    int i;
    if (bid < 8192)      { src = seq; dst = seqb;                      i = bid * 256 + threadIdx.x; }
    else if (bid < 8704) { src = Wq;  dst = Wb;                        i = (bid - 8192) * 256 + threadIdx.x; }
    else if (bid < 9216) { src = Wk;  dst = Wb + (size_t)FF * DD;      i = (bid - 8704) * 256 + threadIdx.x; }
    else                 { src = Wv;  dst = Wb + (size_t)2 * FF * DD;  i = (bid - 9216) * 256 + threadIdx.x; }
    f32x4 a = ((const f32x4*)src)[2 * i];
    f32x4 b = ((const f32x4*)src)[2 * i + 1];
    bf16x8 o;
#pragma unroll
    for (int j = 0; j < 4; ++j) { o[j] = bf16_bits(a[j]); o[4 + j] = bf16_bits(b[j]); }
    ((bf16x8*)dst)[i] = o;
}

// ---------------------------------------------------------------------------
// Shared bf16 GEMM core, BK=64: C[128x128] = A[128xK] @ B[128xK]^T (K-major).
// 256 thr = 4 waves (2x2); wave = 64x64 via 4x4 MFMA subtiles, 2 k-subs/step.
// LDS [128][64] bf16 per operand (32 KB total), swizzled chunks:
//   slot s (16B) -> row s>>3, c_lds = s&7, holds global chunk (c_lds - row)&7.
//   reader: chunk cg at row -> c_lds = (cg + row)&7  => 2-way banks (free).
// Staging via global_load_lds width=16, lane-contiguous LDS (m104-safe).
// Half the barrier drains of BK=32 (the measured ~20% stall of this
// structure); 32 KB LDS keeps ~3 blocks/CU (m132's BK=128/64KB regression
// avoided).
// ---------------------------------------------------------------------------
__device__ __forceinline__ void gemm_core(
    const short* __restrict__ A, int lda, int m0,
    const short* __restrict__ B, int ldb, int n0,
    int K, short* As, short* Bs, f32x4 acc[4][4])
{
    const int tid  = threadIdx.x;
    const int lane = tid & 63;
    const int w    = tid >> 6;
    const int wm   = (w & 1) * 64;
    const int wn   = (w >> 1) * 64;
    const int r    = lane & 15;
    const int qd   = lane >> 4;

    for (int k0 = 0; k0 < K; k0 += 64) {
        __syncthreads();
#pragma unroll
        for (int it = 0; it < 4; ++it) {
            const int s   = tid + it * 256;
            const int row = s >> 3;
            const int col = (((s & 7) - (row & 7)) & 7) << 3;   // swizzled global chunk
            __builtin_amdgcn_global_load_lds(
                (const __attribute__((address_space(1))) unsigned int*)
                    (A + (size_t)(m0 + row) * lda + k0 + col),
                (__attribute__((address_space(3))) unsigned int*)(As + s * 8),
                16, 0, 0);
            __builtin_amdgcn_global_load_lds(
                (const __attribute__((address_space(1))) unsigned int*)
                    (B + (size_t)(n0 + row) * ldb + k0 + col),
                (__attribute__((address_space(3))) unsigned int*)(Bs + s * 8),
                16, 0, 0);
        }
        __syncthreads();
#pragma unroll
        for (int kk = 0; kk < 2; ++kk) {
            bf16x8 af[4], bf[4];
#pragma unroll
            for (int m = 0; m < 4; ++m) {
                const int R = wm + m * 16 + r;
                af[m] = *(const bf16x8*)(As + R * 64 + (((kk * 4 + qd) + R) & 7) * 8);
            }
#pragma unroll
            for (int n = 0; n < 4; ++n) {
                const int R = wn + n * 16 + r;
                bf[n] = *(const bf16x8*)(Bs + R * 64 + (((kk * 4 + qd) + R) & 7) * 8);
            }
#pragma unroll
            for (int m = 0; m < 4; ++m)
#pragma unroll
                for (int n = 0; n < 4; ++n)
                    acc[m][n] = __builtin_amdgcn_mfma_f32_16x16x32_bf16(af[m], bf[n], acc[m][n], 0, 0, 0);
        }
    }
}

// ---------------------------------------------------------------------------
// Kernel 1: q/k = seqb @ Wb^T + bias (bf16 in/out); v transposed vT[b][f][t].
// Grid 3072: nt/proj fastest (24 consecutive blocks share the A row-stripe).
// ---------------------------------------------------------------------------
__global__ __launch_bounds__(256) void qkv_tiled(
    const short* __restrict__ seqb, const short* __restrict__ Wb,
    const float* __restrict__ bq, const float* __restrict__ bk,
    const float* __restrict__ bv,
    __hip_bfloat16* __restrict__ q, __hip_bfloat16* __restrict__ k,
    __hip_bfloat16* __restrict__ vT)
{
    __shared__ short As[128 * 64], Bs[128 * 64];
    const int bid  = blockIdx.x;
    const int mt   = bid / 24;
    const int rest = bid % 24;
    const int nt   = rest & 7;
    const int proj = rest >> 3;

    const short* W    = Wb + (size_t)proj * FF * DD;
    const float* bias = proj == 0 ? bq : (proj == 1 ? bk : bv);

    f32x4 acc[4][4];
#pragma unroll
    for (int m = 0; m < 4; ++m)
#pragma unroll
        for (int n = 0; n < 4; ++n) acc[m][n] = (f32x4){0.f, 0.f, 0.f, 0.f};

    gemm_core(seqb, DD, mt * 128, W, DD, nt * 128, DD, As, Bs, acc);

    const int lane = threadIdx.x & 63;
    const int w    = threadIdx.x >> 6;
    const int wm   = (w & 1) * 64;
    const int wn   = (w >> 1) * 64;
    const int r    = lane & 15;
    const int qd   = lane >> 4;
    const int row_base = mt * 128 + wm + qd * 4;   // +m*16+i
    const int col_base = nt * 128 + wn + r;        // +n*16

    if (proj < 2) {
        __hip_bfloat16* dst = (proj == 0) ? q : k;
#pragma unroll
        for (int n = 0; n < 4; ++n) {
            const int col = col_base + n * 16;
            const float bv_ = bias[col];
#pragma unroll
            for (int m = 0; m < 4; ++m)
#pragma unroll
                for (int i = 0; i < 4; ++i)
                    dst[(size_t)(row_base + m * 16 + i) * FF + col] =
                        __float2bfloat16(acc[m][n][i] + bv_);
        }
    } else {
        // transposed V: lane's 4 regs = 4 consecutive t -> 8B packed store
#pragma unroll
        for (int m = 0; m < 4; ++m) {
            const int rowg = row_base + m * 16;
            const int b_   = rowg >> 11;
            const int t_   = rowg & 2047;
            __hip_bfloat16* vb = vT + (size_t)b_ * FF * TT;
#pragma unroll
            for (int n = 0; n < 4; ++n) {
                const int col = col_base + n * 16;
                const float bv_ = bias[col];
                s16x4 pack;
#pragma unroll
                for (int i = 0; i < 4; ++i) pack[i] = bf16_bits(acc[m][n][i] + bv_);
                *(s16x4*)(vb + (size_t)col * TT + t_) = pack;
            }
        }
    }
}

// ---------------------------------------------------------------------------
// Kernel 2: P[b][t][s] = exp(scale*q.k) bf16 (unnormalized), Z[b][t] += rowsum
// of bf16-rounded values.  Grid: 8 * 256 (st fastest -> q-tile reuse).
// ---------------------------------------------------------------------------
__global__ __launch_bounds__(256) void score_tiled(
    const __hip_bfloat16* __restrict__ q, const __hip_bfloat16* __restrict__ k,
    __hip_bfloat16* __restrict__ P, float* __restrict__ Z)
{
    __shared__ short As[128 * 64], Bs[128 * 64];
    const int bid = blockIdx.x;
    const int b   = bid >> 8;
    const int rem = bid & 255;
    const int tt  = rem >> 4;
    const int st  = rem & 15;

    const short* qb = (const short*)q + (size_t)b * TT * FF;
    const short* kb = (const short*)k + (size_t)b * TT * FF;

    f32x4 acc[4][4];
#pragma unroll
    for (int m = 0; m < 4; ++m)
#pragma unroll
        for (int n = 0; n < 4; ++n) acc[m][n] = (f32x4){0.f, 0.f, 0.f, 0.f};

    gemm_core(qb, FF, tt * 128, kb, FF, st * 128, FF, As, Bs, acc);

    const int lane = threadIdx.x & 63;
    const int w    = threadIdx.x >> 6;
    const int wm   = (w & 1) * 64;
    const int wn   = (w >> 1) * 64;
    const int r    = lane & 15;
    const int qd   = lane >> 4;
    const int row_base = tt * 128 + wm + qd * 4;
    const int col_base = st * 128 + wn + r;

    __hip_bfloat16* Pb = P + (size_t)b * TT * TT;
    float* Zb = Z + b * TT;

    float rs[4][4];
#pragma unroll
    for (int m = 0; m < 4; ++m)
#pragma unroll
        for (int i = 0; i < 4; ++i) rs[m][i] = 0.f;

#pragma unroll
    for (int m = 0; m < 4; ++m)
#pragma unroll
        for (int n = 0; n < 4; ++n) {
            const int col = col_base + n * 16;
#pragma unroll
            for (int i = 0; i < 4; ++i) {
                const float e = exp2f(acc[m][n][i] * kScaleLog2e);
                const __hip_bfloat16 eb = __float2bfloat16(e);
                rs[m][i] += __bfloat162float(eb);
                Pb[(size_t)(row_base + m * 16 + i) * TT + col] = eb;
            }
        }
#pragma unroll
    for (int off = 1; off < 16; off <<= 1)
#pragma unroll
        for (int m = 0; m < 4; ++m)
#pragma unroll
            for (int i = 0; i < 4; ++i) rs[m][i] += __shfl_xor(rs[m][i], off, 64);
    if (r == 0) {
#pragma unroll
        for (int m = 0; m < 4; ++m)
#pragma unroll
            for (int i = 0; i < 4; ++i)
                atomicAdd(&Zb[row_base + m * 16 + i], rs[m][i]);
    }
}

// ---------------------------------------------------------------------------
// Kernel 3: out[b][t][f] = (P @ V)/Z via vT.  Grid: 8 * 128 (ft fastest).
// ---------------------------------------------------------------------------
__global__ __launch_bounds__(256) void pv_tiled(
    const __hip_bfloat16* __restrict__ P, const __hip_bfloat16* __restrict__ vT,
    const float* __restrict__ Z, float* __restrict__ out)
{
    __shared__ short As[128 * 64], Bs[128 * 64];
    const int bid = blockIdx.x;
    const int b   = bid >> 7;
    const int rem = bid & 127;
    const int tt  = rem >> 3;
    const int ft  = rem & 7;

    const short* Pb = (const short*)P + (size_t)b * TT * TT;
    const short* vb = (const short*)vT + (size_t)b * FF * TT;

    f32x4 acc[4][4];
#pragma unroll
    for (int m = 0; m < 4; ++m)
#pragma unroll
        for (int n = 0; n < 4; ++n) acc[m][n] = (f32x4){0.f, 0.f, 0.f, 0.f};

    gemm_core(Pb, TT, tt * 128, vb, TT, ft * 128, TT, As, Bs, acc);

    const int lane = threadIdx.x & 63;
    const int w    = threadIdx.x >> 6;
    const int wm   = (w & 1) * 64;
    const int wn   = (w >> 1) * 64;
    const int r    = lane & 15;
    const int qd   = lane >> 4;
    const int row_base = tt * 128 + wm + qd * 4;
    const int col_base = ft * 128 + wn + r;

    const float* Zb = Z + b * TT;
    float* ob = out + (size_t)b * TT * FF;

#pragma unroll
    for (int m = 0; m < 4; ++m) {
        float rz[4];
#pragma unroll
        for (int i = 0; i < 4; ++i) rz[i] = 1.0f / Zb[row_base + m * 16 + i];
#pragma unroll
        for (int n = 0; n < 4; ++n) {
            const int col = col_base + n * 16;
#pragma unroll
            for (int i = 0; i < 4; ++i)
                ob[(size_t)(row_base + m * 16 + i) * FF + col] = acc[m][n][i] * rz[i];
        }
    }
}

// ---------------------------------------------------------------------------
extern "C" void kernel_launch(void* const* d_in, const int* in_sizes, int n_in,
                              void* d_out, int out_size, void* d_ws, size_t ws_size,
                              hipStream_t stream) {
    const float* seq = (const float*)d_in[0];
    const float* Wq  = (const float*)d_in[1];
    const float* bq  = (const float*)d_in[2];
    const float* Wk  = (const float*)d_in[3];
    const float* bk  = (const float*)d_in[4];
    const float* Wv  = (const float*)d_in[5];
    const float* bv  = (const float*)d_in[6];
    float* out = (float*)d_out;
    char* ws = (char*)d_ws;

    // Workspace (167,837,696 B — bound proven by round 5's tier-1):
    //   q   : 32 MiB @ 0
    //   k   : 32 MiB @ 33554432
    //   vT  : 32 MiB @ 67108864
    //   P   : 64 MiB @ 100663296   (seqb [32 MiB] + Wb [6 MiB] alias P;
    //                               both dead before score writes P)
    //   Z   : 64 KiB @ 167772160
    const size_t MB32 = 33554432;
    __hip_bfloat16* q   = (__hip_bfloat16*)(ws);
    __hip_bfloat16* k   = (__hip_bfloat16*)(ws + MB32);
    __hip_bfloat16* vT  = (__hip_bfloat16*)(ws + 2 * MB32);
    __hip_bfloat16* P   = (__hip_bfloat16*)(ws + 3 * MB32);
    float*          Z   = (float*)(ws + 3 * MB32 + (size_t)67108864);
    short*          seqb = (short*)P;
    short*          Wb   = (short*)((char*)P + MB32);

    hipMemsetAsync(Z, 0, (size_t)BB * TT * sizeof(float), stream);

    cvt_all<<<9728, 256, 0, stream>>>(seq, Wq, Wk, Wv, seqb, Wb);
    qkv_tiled<<<128 * 24, 256, 0, stream>>>(seqb, Wb, bq, bk, bv, q, k, vT);
    score_tiled<<<BB * 256, 256, 0, stream>>>(q, k, P, Z);
    pv_tiled<<<BB * 128, 256, 0, stream>>>(P, vT, Z, out);
}